// Round 8
// baseline (173.518 us; speedup 1.0000x reference)
//
#include <hip/hip_runtime.h>
#include <utility>

// Gaunt tensor product via exact collapse of the S2-grid path to a sparse
// packed Gaunt tensor (computed on-device from Y_in/Y_out/qw).
//
// K0: per (i,j): G_row[k] = sum_p qw*Y_out[k,p]*Y_in[i,p]*Y_in[j,p], packed.
// K1: proj+Gaunt, ALL 3 BRANCHES per block (x fetched once, 3x intensity).
//     Wave = n, lane = c. x via uniform-address VECTOR loads, double-buffered
//     (vmcnt pipelining, VGPR budget 256). Writes co[n][b][k][d] into d_out.
// K2: mix. 1 wave per (n,b). co rows via uniform s_load; Wout per-lane from
//     L2; in-place overwrite of d_out through an LDS transpose.

#define NN 2048

__host__ __device__ constexpr int l_of9(int i)  { return i < 1 ? 0 : (i < 4 ? 1 : 2); }
__host__ __device__ constexpr int l_of25(int k) { return k < 1 ? 0 : (k < 4 ? 1 : (k < 9 ? 2 : (k < 16 ? 3 : 4))); }
__host__ __device__ constexpr int iabs_(int v)  { return v < 0 ? -v : v; }

__host__ __device__ constexpr bool gmask(int k, int i, int j) {
    const int l3 = l_of25(k), m3 = k - l3 * l3 - l3;
    const int l1 = l_of9(i),  m1 = i - l1 * l1 - l1;
    const int l2 = l_of9(j),  m2 = j - l2 * l2 - l2;
    if (((l1 + l2 + l3) & 1) != 0) return false;
    if (l3 > l1 + l2 || l3 < iabs_(l1 - l2)) return false;
    const int am3 = iabs_(m3);
    return (am3 == iabs_(m1 + m2)) || (am3 == iabs_(m1 - m2));
}

struct GTab {
    int po[82];
    int pc[81];
    int kl[81][12];
    constexpr GTab() : po{}, pc{}, kl{} {
        int off = 0;
        for (int ij = 0; ij < 81; ++ij) {
            po[ij] = off;
            const int i = ij / 9, j = ij % 9;
            int cnum = 0;
            for (int k = 0; k < 25; ++k)
                if (gmask(k, i, j)) kl[ij][cnum++] = k;
            pc[ij] = cnum;
            off += (cnum + 3) & ~3;
        }
        po[81] = off;
    }
};
constexpr GTab GT{};

// ---------------------------------------------------------------------------
// K0: compute + pack G. Grid 81, 256 threads.
// ---------------------------------------------------------------------------
__global__ __launch_bounds__(256) void gaunt_pack_kernel(
    const float* __restrict__ Y_in, const float* __restrict__ Y_out,
    const float* __restrict__ qw, float* __restrict__ gp)
{
    const int ij = blockIdx.x;
    const int i = ij / 9, j = ij % 9;
    const int t = threadIdx.x;

    __shared__ float yy[780];
    __shared__ float ps[25][8];
    __shared__ float gr[25];

    for (int p = t; p < 780; p += 256)
        yy[p] = Y_in[i * 780 + p] * Y_in[j * 780 + p] * qw[p / 39];
    __syncthreads();

    if (t < 200) {
        const int k = t >> 3, s = t & 7;
        const float* yo = Y_out + k * 780;
        const int p1 = (s * 98 + 98 < 780) ? (s * 98 + 98) : 780;
        float a = 0.f;
        for (int p = s * 98; p < p1; ++p) a = fmaf(yy[p], yo[p], a);
        ps[k][s] = a;
    }
    __syncthreads();

    if (t < 25) {
        float a = 0.f;
#pragma unroll
        for (int s = 0; s < 8; ++s) a += ps[t][s];
        gr[t] = a;
    }
    __syncthreads();

    const int cntp = (GT.pc[ij] + 3) & ~3;
    if (t < cntp)
        gp[GT.po[ij] + t] = (t < GT.pc[ij]) ? gr[GT.kl[ij][t]] : 0.f;
}

// ---------------------------------------------------------------------------
// Sparse in-register Gaunt with compile-time indices (gp loads uniform).
// ---------------------------------------------------------------------------
template <int IJ, int... Ts>
__device__ __forceinline__ void gaunt_apply(const float (&g)[12], float pij,
    float (&cov)[25], std::integer_sequence<int, Ts...>)
{
    ((cov[GT.kl[IJ][Ts]] = fmaf(g[Ts], pij, cov[GT.kl[IJ][Ts]])), ...);
}

template <int IJ>
__device__ __forceinline__ void gaunt_pair(const float* __restrict__ gp,
    const float (&c1)[9], const float (&c2)[9], float (&cov)[25])
{
    constexpr int cnt = GT.pc[IJ];
    if constexpr (cnt > 0) {
        constexpr int base = GT.po[IJ];
        constexpr int nv = (cnt + 3) / 4;
        const float pij = c1[IJ / 9] * c2[IJ % 9];
        float g[12];
#pragma unroll
        for (int q = 0; q < nv; ++q) {
            const float4 v = ((const float4*)(gp + base))[q];
            g[4 * q] = v.x; g[4 * q + 1] = v.y; g[4 * q + 2] = v.z; g[4 * q + 3] = v.w;
        }
        gaunt_apply<IJ>(g, pij, cov, std::make_integer_sequence<int, cnt>{});
    }
}

template <int I, int... Js>
__device__ __forceinline__ void gaunt_row(const float* __restrict__ gp,
    const float (&c1)[9], const float (&c2)[9], float (&cov)[25],
    std::integer_sequence<int, Js...>)
{
    (gaunt_pair<I * 9 + Js>(gp, c1, c2, cov), ...);
    __builtin_amdgcn_sched_barrier(0);   // bound live ranges per row
}

template <int... Is>
__device__ __forceinline__ void gaunt_all(const float* __restrict__ gp,
    const float (&c1)[9], const float (&c2)[9], float (&cov)[25],
    std::integer_sequence<int, Is...>)
{
    (gaunt_row<Is>(gp, c1, c2, cov, std::make_integer_sequence<int, 9>{}), ...);
}

// ---------------------------------------------------------------------------
// K1 helpers.
// ---------------------------------------------------------------------------
__device__ __forceinline__ void load_x9(const float4* __restrict__ p,
                                        float4 (&v)[9])
{
#pragma unroll
    for (int q = 0; q < 9; ++q) v[q] = p[q];
}

template <int E1, int E2>
__device__ __forceinline__ void proj_step(const float (&xs1)[36],
    const float (&xs2)[36], const float* __restrict__ W1p,
    const float* __restrict__ W2p, float (&a1)[9], float (&a2)[9])
{
#pragma unroll
    for (int l = 0; l < 3; ++l) {
        const int O1 = ((l & 1) ^ E1) * 9 + l * l;
        const int O2 = ((l & 1) ^ E2) * 9 + l * l;
#pragma unroll
        for (int mi = 0; mi < 2; ++mi) {
            const float w1v = W1p[l * 4096 + mi * 64];
            const float w2v = W2p[l * 4096 + mi * 64];
#pragma unroll
            for (int ii = 0; ii <= 2 * l; ++ii) {
                a1[l*l+ii] = fmaf(xs1[O1 + 18*mi + ii], w1v, a1[l*l+ii]);
                a2[l*l+ii] = fmaf(xs2[O2 + 18*mi + ii], w2v, a2[l*l+ii]);
            }
        }
    }
}

// ---------------------------------------------------------------------------
// K1: all 3 branches per block. Wave w -> n = bx*4+w, lane = c. No LDS.
// x loads: uniform-address vector float4, double-buffered (A/B ping-pong).
// ---------------------------------------------------------------------------
__global__ __launch_bounds__(256, 2) void fused_kernel(
    const float* __restrict__ x1, const float* __restrict__ x2,
    const float* __restrict__ W1, const float* __restrict__ W2,
    const float* __restrict__ gp, float* __restrict__ out)
{
    const int t = threadIdx.x;
    const int c = t & 63;
    const int w = t >> 6;                 // NOT readfirstlane: keep vector loads
    const int n = blockIdx.x * 4 + w;

    const float4* px1 = (const float4*)(x1 + (size_t)n * 1152);
    const float4* px2 = (const float4*)(x2 + (size_t)n * 1152);
    const float* W1c = W1 + c;
    const float* W2c = W2 + c;

    float a1[3][9], a2[3][9];
#pragma unroll
    for (int b = 0; b < 3; ++b)
#pragma unroll
        for (int i = 0; i < 9; ++i) { a1[b][i] = 0.f; a2[b][i] = 0.f; }

    float4 xA1[9], xA2[9], xB1[9], xB2[9];
    load_x9(px1, xA1);
    load_x9(px2, xA2);

    auto do_pair = [&](const float4 (&v1)[9], const float4 (&v2)[9], int mp) {
        float xs1[36], xs2[36];
#pragma unroll
        for (int q = 0; q < 9; ++q) {
            xs1[4*q] = v1[q].x; xs1[4*q+1] = v1[q].y;
            xs1[4*q+2] = v1[q].z; xs1[4*q+3] = v1[q].w;
            xs2[4*q] = v2[q].x; xs2[4*q+1] = v2[q].y;
            xs2[4*q+2] = v2[q].z; xs2[4*q+3] = v2[q].w;
        }
        const float* W1p = W1c + mp * 128;
        const float* W2p = W2c + mp * 128;
        proj_step<0, 0>(xs1, xs2, W1p,         W2p,         a1[0], a2[0]);
        proj_step<0, 1>(xs1, xs2, W1p + 12288, W2p + 12288, a1[1], a2[1]);
        proj_step<1, 0>(xs1, xs2, W1p + 24576, W2p + 24576, a1[2], a2[2]);
    };

#pragma unroll 1
    for (int mp = 0; mp < 32; mp += 2) {
        load_x9(px1 + (mp + 1) * 9, xB1);     // prefetch odd pair
        load_x9(px2 + (mp + 1) * 9, xB2);
        do_pair(xA1, xA2, mp);
        if (mp + 2 < 32) {
            load_x9(px1 + (mp + 2) * 9, xA1); // prefetch next even pair
            load_x9(px2 + (mp + 2) * 9, xA2);
        }
        do_pair(xB1, xB2, mp + 1);
    }

    // ---- per branch: scale, Gaunt, store co[n][b][k][d=c] ----
#pragma unroll
    for (int b = 0; b < 3; ++b) {
        float c1[9], c2[9];
#pragma unroll
        for (int i = 0; i < 9; ++i) {
            c1[i] = a1[b][i] * 0.125f;
            c2[i] = a2[b][i] * 0.125f;
        }
        float cov[25] = {0,0,0,0,0,0,0,0,0,0,0,0,0,0,0,0,0,0,0,0,0,0,0,0,0};
        gaunt_all(gp, c1, c2, cov, std::make_integer_sequence<int, 9>{});

        float* cob = out + ((size_t)n * 3 + b) * 1600 + c;
#pragma unroll
        for (int k = 0; k < 25; ++k) cob[k * 64] = cov[k];
    }
}

// ---------------------------------------------------------------------------
// K2: mix, 1 wave per (n,b). co rows via uniform s_load; W per-lane; LDS
// transpose for coalesced float4 stores; in-place on d_out.
// ---------------------------------------------------------------------------
__global__ __launch_bounds__(64, 6) void mix_kernel(
    const float* __restrict__ Wout, float* __restrict__ io)
{
    const int n = blockIdx.x;
    const int b = blockIdx.y;
    const int c = threadIdx.x;   // 0..63

    __shared__ float st[1600];

    const float* cob = io + ((size_t)n * 3 + b) * 1600;   // [k][d]
    const float* WoB = Wout + (size_t)b * 5 * 4096 + c;

    float acc[25];
#pragma unroll
    for (int k = 0; k < 25; ++k) acc[k] = 0.f;

#pragma unroll 1
    for (int dc = 0; dc < 16; ++dc) {
        const int d0 = dc * 4;
        float wr[5][4];
#pragma unroll
        for (int l3 = 0; l3 < 5; ++l3)
#pragma unroll
            for (int q = 0; q < 4; ++q)
                wr[l3][q] = WoB[(size_t)(l3 * 64 + d0 + q) * 64];

#pragma unroll
        for (int kg = 0; kg < 5; ++kg) {
#pragma unroll
            for (int kk = 0; kk < 5; ++kk) {
                const int k = kg * 5 + kk;
                const int l3 = l_of25(k);
                const float4 cv = *(const float4*)(cob + k * 64 + d0);
                acc[k] = fmaf(cv.x, wr[l3][0], acc[k]);
                acc[k] = fmaf(cv.y, wr[l3][1], acc[k]);
                acc[k] = fmaf(cv.z, wr[l3][2], acc[k]);
                acc[k] = fmaf(cv.w, wr[l3][3], acc[k]);
            }
            __builtin_amdgcn_sched_barrier(0);   // keep s_load bursts small
        }
    }

    // ---- transpose [d=c][k] -> linear [c][k] in LDS, then float4 stores ----
#pragma unroll
    for (int k = 0; k < 25; ++k) st[c * 25 + k] = acc[k] * 0.125f;
    __syncthreads();

    float* op = io + ((size_t)n * 3 + b) * 1600;
#pragma unroll
    for (int r = 0; r < 6; ++r) {
        const float4 v = *(const float4*)&st[(r * 64 + c) * 4];
        *(float4*)(op + (r * 64 + c) * 4) = v;
    }
    if (c < 16) {
        const float4 v = *(const float4*)&st[(384 + c) * 4];
        *(float4*)(op + (384 + c) * 4) = v;
    }
}

extern "C" void kernel_launch(void* const* d_in, const int* in_sizes, int n_in,
                              void* d_out, int out_size, void* d_ws, size_t ws_size,
                              hipStream_t stream) {
    const float* x1    = (const float*)d_in[0];
    const float* x2    = (const float*)d_in[1];
    const float* W1    = (const float*)d_in[2];
    const float* W2    = (const float*)d_in[3];
    const float* Wout  = (const float*)d_in[4];
    const float* Y_in  = (const float*)d_in[5];
    const float* Y_out = (const float*)d_in[6];
    const float* qw    = (const float*)d_in[7];
    float* outp = (float*)d_out;
    float* gp   = (float*)d_ws;

    gaunt_pack_kernel<<<81, 256, 0, stream>>>(Y_in, Y_out, qw, gp);
    fused_kernel<<<NN / 4, 256, 0, stream>>>(x1, x2, W1, W2, gp, outp);
    mix_kernel<<<dim3(NN, 3), 64, 0, stream>>>(Wout, outp);
}